// Round 1
// baseline (2207.301 us; speedup 1.0000x reference)
//
#include <hip/hip_runtime.h>
#include <cstdint>

#define B_   128
#define T_   2048
#define E_   8
#define OUT_ 32
#define HID_ 64
#define KC_  8

__device__ __forceinline__ float fsig(float x) {
  return 1.0f / (1.0f + __expf(-x));
}

__device__ __forceinline__ float ftanh_(float x) {
  float ax = fabsf(x);
  float e = __expf(2.0f * ax);
  float t = 1.0f - 2.0f / (e + 1.0f);
  return copysignf(t, x);
}

__device__ __forceinline__ float rlane(float v, int i) {
  return __int_as_float(__builtin_amdgcn_readlane(__float_as_int(v), i));
}

// Per-(b,t) scalar KAN pieces: silu(x), softmax gate[8], b-spline basis bs[8].
__device__ __forceinline__ void kan_scalars(float x, const float* gwr, const float* gbr,
                                            float& silu, float* gate, float* bs) {
  silu = x * fsig(x);
  float le[E_];
  float m = -1e30f;
#pragma unroll
  for (int e = 0; e < E_; ++e) { le[e] = fmaf(x, gwr[e], gbr[e]); m = fmaxf(m, le[e]); }
  float s = 0.f;
#pragma unroll
  for (int e = 0; e < E_; ++e) { gate[e] = __expf(le[e] - m); s += gate[e]; }
  float inv = 1.0f / s;
#pragma unroll
  for (int e = 0; e < E_; ++e) gate[e] *= inv;
  // extended knot grid, exactly as reference: (i-3)*0.4f - 1.0f
  float g[12];
#pragma unroll
  for (int i = 0; i < 12; ++i) g[i] = (float)(i - 3) * 0.4f - 1.0f;
  float bb[11];
#pragma unroll
  for (int i = 0; i < 11; ++i) bb[i] = (x >= g[i] && x < g[i + 1]) ? 1.0f : 0.0f;
#pragma unroll
  for (int k = 1; k <= 3; ++k) {
#pragma unroll
    for (int i = 0; i < 11 - k; ++i) {
      float left  = (x - g[i]) / (g[i + k] - g[i]);
      float right = (g[i + k + 1] - x) / (g[i + k + 1] - g[i + 1]);
      bb[i] = left * bb[i] + right * bb[i + 1];
    }
  }
#pragma unroll
  for (int i = 0; i < KC_; ++i) bs[i] = bb[i];
}

// ---------------- Kernel A: KAN(a) fused with Conv1d(k=5,'SAME') + ReLU -> out[:,:,0:32]
#define TILE_A 128
__global__ __launch_bounds__(256) void kan_conv_kernel(
    const float* __restrict__ a, const float* __restrict__ gw, const float* __restrict__ gb,
    const float* __restrict__ bw, const float* __restrict__ sw,
    const float* __restrict__ cw, const float* __restrict__ cb, float* __restrict__ out)
{
  __shared__ float fa[OUT_][TILE_A + 8];   // [c][i], i = t - t0 + 2, padded row for bank spread
  __shared__ float cwl[OUT_][161];         // conv weights [o][c*5+j], padded
  __shared__ float swl[E_][OUT_][KC_];
  __shared__ float bwl[E_][OUT_];
  __shared__ float gwl[E_], gbl[E_];
  const int tid = threadIdx.x;
  const int b = blockIdx.y;
  const int t0 = blockIdx.x * TILE_A;

  for (int i = tid; i < OUT_ * OUT_ * 5; i += 256) cwl[i / 160][i % 160] = cw[i];
  for (int i = tid; i < E_ * OUT_ * KC_; i += 256) ((float*)swl)[i] = sw[i];
  for (int i = tid; i < E_ * OUT_; i += 256) ((float*)bwl)[i] = bw[i];
  if (tid < E_) { gwl[tid] = gw[tid]; gbl[tid] = gb[tid]; }
  __syncthreads();

  // phase 1: KAN features for t in [t0-2, t0+TILE_A+2)
  if (tid < TILE_A + 4) {
    const int i = tid;
    const int t = t0 + i - 2;
    const bool inr = (t >= 0) && (t < T_);
    const float x = inr ? a[(size_t)b * T_ + t] : 0.0f;
    float gwr[E_], gbr[E_];
#pragma unroll
    for (int e = 0; e < E_; ++e) { gwr[e] = gwl[e]; gbr[e] = gbl[e]; }
    float silu, gate[E_], bs[KC_];
    kan_scalars(x, gwr, gbr, silu, gate, bs);
#pragma unroll 4
    for (int cc = 0; cc < OUT_; ++cc) {
      float accb = 0.f, accs = 0.f;
#pragma unroll
      for (int e = 0; e < E_; ++e) {
        accb = fmaf(gate[e], bwl[e][cc], accb);
        const float4 s0 = *(const float4*)&swl[e][cc][0];
        const float4 s1 = *(const float4*)&swl[e][cc][4];
        float dot = bs[0]*s0.x + bs[1]*s0.y + bs[2]*s0.z + bs[3]*s0.w
                  + bs[4]*s1.x + bs[5]*s1.y + bs[6]*s1.z + bs[7]*s1.w;
        accs = fmaf(gate[e], dot, accs);
      }
      // conv 'SAME' zero-pads the FEATURE map, so OOR t -> 0 (not KAN(0))
      fa[cc][i] = inr ? fmaf(silu, accb, accs) : 0.0f;
    }
  }
  __syncthreads();

  // phase 2: conv over the tile. thread = (o = tid&31, grp = tid>>5 handles 16 t's)
  const int o = tid & 31;
  const int grp = tid >> 5;
  const float bias = cb[o];
  float acc[16];
#pragma unroll
  for (int it = 0; it < 16; ++it) acc[it] = bias;
  for (int c = 0; c < OUT_; ++c) {
    float col[20];
#pragma unroll
    for (int q = 0; q < 5; ++q)
      *(float4*)&col[q * 4] = *(const float4*)&fa[c][grp * 16 + q * 4];
#pragma unroll
    for (int jj = 0; jj < 5; ++jj) {
      const float wv = cwl[o][c * 5 + jj];
#pragma unroll
      for (int it = 0; it < 16; ++it) acc[it] = fmaf(col[it + jj], wv, acc[it]);
    }
  }
#pragma unroll
  for (int it = 0; it < 16; ++it) {
    const int t = t0 + grp * 16 + it;
    out[((size_t)b * T_ + t) * 96 + o] = fmaxf(acc[it], 0.0f);
  }
}

// ---------------- Kernel B: KAN(d) fused with sequential GRU -> out[:,:,32:96]
// One block per batch row. Waves 0..2 own gate rows g = w*64 + j with weights in VGPRs;
// h is register-replicated per wave (lane j = h[j]) and broadcast via v_readlane.
__global__ __launch_bounds__(256, 1) void gru_kernel(
    const float* __restrict__ d, const float* __restrict__ gw, const float* __restrict__ gb,
    const float* __restrict__ bw, const float* __restrict__ sw,
    const float* __restrict__ wih_g, const float* __restrict__ whh_g,
    const float* __restrict__ bih_g, const float* __restrict__ bhh_g,
    float* __restrict__ out)
{
  __shared__ float packs[64][17];    // per t in chunk: silu, gate[8], bs[8]
  __shared__ float fdbuf[64][33];    // fd chunk [t_local][c], padded
  __shared__ float sb[2][256];       // dbl-buffered: pre_r[64] | pre_z[64] | xn[64] | hn[64]
  const int tid = threadIdx.x;
  const int b = blockIdx.x;
  const int w = tid >> 6;
  const int j = tid & 63;
  const int c = tid & 31;

  // per-channel KAN-d weights in registers (channel = c, all threads)
  float swr[E_][KC_], bwr[E_];
#pragma unroll
  for (int e = 0; e < E_; ++e) {
    const float4 s0 = *(const float4*)&sw[(e * OUT_ + c) * KC_ + 0];
    const float4 s1 = *(const float4*)&sw[(e * OUT_ + c) * KC_ + 4];
    swr[e][0] = s0.x; swr[e][1] = s0.y; swr[e][2] = s0.z; swr[e][3] = s0.w;
    swr[e][4] = s1.x; swr[e][5] = s1.y; swr[e][6] = s1.z; swr[e][7] = s1.w;
    bwr[e] = bw[e * OUT_ + c];
  }
  float gwr[E_], gbr[E_];
#pragma unroll
  for (int e = 0; e < E_; ++e) { gwr[e] = gw[e]; gbr[e] = gb[e]; }

  // GRU weights: thread t<192 owns gate row t
  float whh[64], wih[32];
  float bhhr = 0.f, bihr = 0.f;
  if (tid < 192) {
#pragma unroll
    for (int i = 0; i < 64; i += 4)
      *(float4*)&whh[i] = *(const float4*)&whh_g[(size_t)tid * 64 + i];
#pragma unroll
    for (int i = 0; i < 32; i += 4)
      *(float4*)&wih[i] = *(const float4*)&wih_g[(size_t)tid * 32 + i];
    bhhr = bhh_g[tid]; bihr = bih_g[tid];
  }

  float h = 0.0f;                          // lane j's copy of h[j], replicated per wave
  float* outrow = out + (size_t)b * T_ * 96 + 32;

  for (int tc = 0; tc < T_; tc += 64) {
    // pack phase: wave 0 computes scalar KAN pieces for the 64 t's of this chunk
    if (tid < 64) {
      const float x = d[(size_t)b * T_ + tc + tid];
      float silu, gate[E_], bs[KC_];
      kan_scalars(x, gwr, gbr, silu, gate, bs);
      packs[tid][0] = silu;
#pragma unroll
      for (int e = 0; e < E_; ++e) packs[tid][1 + e] = gate[e];
#pragma unroll
      for (int k = 0; k < KC_; ++k) packs[tid][9 + k] = bs[k];
    }
    __syncthreads();
    // fd phase: all 256 threads; thread (c, grp) fills fd for 8 t's at its channel
    {
      const int grp = tid >> 5;
#pragma unroll
      for (int s8 = 0; s8 < 8; ++s8) {
        const int tl = grp * 8 + s8;
        const float silu = packs[tl][0];
        float gatev[E_], bsv[KC_];
#pragma unroll
        for (int e = 0; e < E_; ++e) gatev[e] = packs[tl][1 + e];
#pragma unroll
        for (int k = 0; k < KC_; ++k) bsv[k] = packs[tl][9 + k];
        float accb = 0.f, accs = 0.f;
#pragma unroll
        for (int e = 0; e < E_; ++e) {
          accb = fmaf(gatev[e], bwr[e], accb);
          float dot = bsv[0]*swr[e][0] + bsv[1]*swr[e][1] + bsv[2]*swr[e][2] + bsv[3]*swr[e][3]
                    + bsv[4]*swr[e][4] + bsv[5]*swr[e][5] + bsv[6]*swr[e][6] + bsv[7]*swr[e][7];
          accs = fmaf(gatev[e], dot, accs);
        }
        fdbuf[tl][c] = fmaf(silu, accb, accs);
      }
    }
    __syncthreads();

    // 64 sequential GRU steps, ONE barrier per step (double-buffered sb)
    for (int s = 0; s < 64; ++s) {
      if (w < 3) {
        // hp = b_hh[g] + dot(h, w_hh[g,:])  via readlane broadcast, 4 acc chains
        float a0 = 0.f, a1 = 0.f, a2 = 0.f, a3 = 0.f;
#pragma unroll
        for (int i = 0; i < 64; i += 4) {
          a0 = fmaf(rlane(h, i + 0), whh[i + 0], a0);
          a1 = fmaf(rlane(h, i + 1), whh[i + 1], a1);
          a2 = fmaf(rlane(h, i + 2), whh[i + 2], a2);
          a3 = fmaf(rlane(h, i + 3), whh[i + 3], a3);
        }
        const float hp = bhhr + ((a0 + a1) + (a2 + a3));
        // xp = b_ih[g] + dot(fd_t, w_ih[g,:])
        const float fdv = fdbuf[s][c];   // lane i (i<32) holds fd[i]
        float x0 = 0.f, x1 = 0.f;
#pragma unroll
        for (int i = 0; i < 32; i += 2) {
          x0 = fmaf(rlane(fdv, i + 0), wih[i + 0], x0);
          x1 = fmaf(rlane(fdv, i + 1), wih[i + 1], x1);
        }
        const float xp = bihr + (x0 + x1);
        const int p = s & 1;
        if (w == 0)      sb[p][j] = hp + xp;            // r pre-activation
        else if (w == 1) sb[p][64 + j] = hp + xp;       // z pre-activation
        else             { sb[p][128 + j] = xp; sb[p][192 + j] = hp; }  // xn, hn
      }
      __syncthreads();
      if (w < 3) {
        const int p = s & 1;
        const float pr = sb[p][j];
        const float pz = sb[p][64 + j];
        const float xn = sb[p][128 + j];
        const float hn = sb[p][192 + j];
        const float r = fsig(pr);
        const float z = fsig(pz);
        const float n = ftanh_(fmaf(r, hn, xn));
        h = (1.0f - z) * n + z * h;
        if (w == 0) outrow[(size_t)(tc + s) * 96 + j] = h;
      }
    }
  }
}

extern "C" void kernel_launch(void* const* d_in, const int* in_sizes, int n_in,
                              void* d_out, int out_size, void* d_ws, size_t ws_size,
                              hipStream_t stream) {
  (void)in_sizes; (void)n_in; (void)out_size; (void)d_ws; (void)ws_size;
  const float* a        = (const float*)d_in[0];
  const float* d        = (const float*)d_in[1];
  const float* gate_w_a = (const float*)d_in[2];
  const float* gate_b_a = (const float*)d_in[3];
  const float* base_w_a = (const float*)d_in[4];
  const float* spln_w_a = (const float*)d_in[5];
  const float* gate_w_d = (const float*)d_in[6];
  const float* gate_b_d = (const float*)d_in[7];
  const float* base_w_d = (const float*)d_in[8];
  const float* spln_w_d = (const float*)d_in[9];
  const float* conv_w   = (const float*)d_in[10];
  const float* conv_b   = (const float*)d_in[11];
  const float* w_ih     = (const float*)d_in[12];
  const float* w_hh     = (const float*)d_in[13];
  const float* b_ih     = (const float*)d_in[14];
  const float* b_hh     = (const float*)d_in[15];
  float* out = (float*)d_out;

  dim3 gridA(T_ / TILE_A, B_);
  kan_conv_kernel<<<gridA, 256, 0, stream>>>(a, gate_w_a, gate_b_a, base_w_a, spln_w_a,
                                             conv_w, conv_b, out);
  gru_kernel<<<B_, 256, 0, stream>>>(d, gate_w_d, gate_b_d, base_w_d, spln_w_d,
                                     w_ih, w_hh, b_ih, b_hh, out);
}

// Round 2
// 1642.961 us; speedup vs baseline: 1.3435x; 1.3435x over previous
//
#include <hip/hip_runtime.h>
#include <cstdint>

#define B_   128
#define T_   2048
#define E_   8
#define OUT_ 32
#define HID_ 64
#define KC_  8

__device__ __forceinline__ float frcp(float x) { return __builtin_amdgcn_rcpf(x); }

__device__ __forceinline__ float fsig(float x) {
  return frcp(1.0f + __expf(-x));
}

__device__ __forceinline__ float ftanh_(float x) {
  float ax = fabsf(x);
  float e = __expf(2.0f * ax);
  float t = 1.0f - 2.0f * frcp(e + 1.0f);
  return copysignf(t, x);
}

__device__ __forceinline__ float rlane(float v, int i) {
  return __int_as_float(__builtin_amdgcn_readlane(__float_as_int(v), i));
}

// Per-(b,t) scalar KAN pieces: silu(x), softmax gate[8], b-spline basis bs[8].
// All b-spline denominators fold to compile-time reciprocal constants (no v_div).
__device__ __forceinline__ void kan_scalars(float x, const float* gwr, const float* gbr,
                                            float& silu, float* gate, float* bs) {
  silu = x * fsig(x);
  float le[E_];
  float m = -1e30f;
#pragma unroll
  for (int e = 0; e < E_; ++e) { le[e] = fmaf(x, gwr[e], gbr[e]); m = fmaxf(m, le[e]); }
  float s = 0.f;
#pragma unroll
  for (int e = 0; e < E_; ++e) { gate[e] = __expf(le[e] - m); s += gate[e]; }
  float inv = frcp(s);
#pragma unroll
  for (int e = 0; e < E_; ++e) gate[e] *= inv;
  float g[12];
#pragma unroll
  for (int i = 0; i < 12; ++i) g[i] = (float)(i - 3) * 0.4f - 1.0f;
  float bb[11];
#pragma unroll
  for (int i = 0; i < 11; ++i) bb[i] = (x >= g[i] && x < g[i + 1]) ? 1.0f : 0.0f;
#pragma unroll
  for (int k = 1; k <= 3; ++k) {
#pragma unroll
    for (int i = 0; i < 11 - k; ++i) {
      const float dl = 1.0f / (g[i + k] - g[i]);          // compile-time constant
      const float dr = 1.0f / (g[i + k + 1] - g[i + 1]);  // compile-time constant
      float left  = (x - g[i]) * dl;
      float right = (g[i + k + 1] - x) * dr;
      bb[i] = left * bb[i] + right * bb[i + 1];
    }
  }
#pragma unroll
  for (int i = 0; i < KC_; ++i) bs[i] = bb[i];
}

// ---------------- Kernel A: KAN(a) fused with Conv1d(k=5,'SAME') + ReLU -> out[:,:,0:32]
#define TILE_A 128
__global__ __launch_bounds__(256) void kan_conv_kernel(
    const float* __restrict__ a, const float* __restrict__ gw, const float* __restrict__ gb,
    const float* __restrict__ bw, const float* __restrict__ sw,
    const float* __restrict__ cw, const float* __restrict__ cb, float* __restrict__ out)
{
  __shared__ float fa[OUT_][TILE_A + 8];
  __shared__ float cwl[OUT_][161];
  __shared__ float swl[E_][OUT_][KC_];
  __shared__ float bwl[E_][OUT_];
  __shared__ float gwl[E_], gbl[E_];
  const int tid = threadIdx.x;
  const int b = blockIdx.y;
  const int t0 = blockIdx.x * TILE_A;

  for (int i = tid; i < OUT_ * OUT_ * 5; i += 256) cwl[i / 160][i % 160] = cw[i];
  for (int i = tid; i < E_ * OUT_ * KC_; i += 256) ((float*)swl)[i] = sw[i];
  for (int i = tid; i < E_ * OUT_; i += 256) ((float*)bwl)[i] = bw[i];
  if (tid < E_) { gwl[tid] = gw[tid]; gbl[tid] = gb[tid]; }
  __syncthreads();

  if (tid < TILE_A + 4) {
    const int i = tid;
    const int t = t0 + i - 2;
    const bool inr = (t >= 0) && (t < T_);
    const float x = inr ? a[(size_t)b * T_ + t] : 0.0f;
    float gwr[E_], gbr[E_];
#pragma unroll
    for (int e = 0; e < E_; ++e) { gwr[e] = gwl[e]; gbr[e] = gbl[e]; }
    float silu, gate[E_], bs[KC_];
    kan_scalars(x, gwr, gbr, silu, gate, bs);
#pragma unroll 4
    for (int cc = 0; cc < OUT_; ++cc) {
      float accb = 0.f, accs = 0.f;
#pragma unroll
      for (int e = 0; e < E_; ++e) {
        accb = fmaf(gate[e], bwl[e][cc], accb);
        const float4 s0 = *(const float4*)&swl[e][cc][0];
        const float4 s1 = *(const float4*)&swl[e][cc][4];
        float dot = bs[0]*s0.x + bs[1]*s0.y + bs[2]*s0.z + bs[3]*s0.w
                  + bs[4]*s1.x + bs[5]*s1.y + bs[6]*s1.z + bs[7]*s1.w;
        accs = fmaf(gate[e], dot, accs);
      }
      fa[cc][i] = inr ? fmaf(silu, accb, accs) : 0.0f;
    }
  }
  __syncthreads();

  const int o = tid & 31;
  const int grp = tid >> 5;
  const float bias = cb[o];
  float acc[16];
#pragma unroll
  for (int it = 0; it < 16; ++it) acc[it] = bias;
  for (int c = 0; c < OUT_; ++c) {
    float col[20];
#pragma unroll
    for (int q = 0; q < 5; ++q)
      *(float4*)&col[q * 4] = *(const float4*)&fa[c][grp * 16 + q * 4];
#pragma unroll
    for (int jj = 0; jj < 5; ++jj) {
      const float wv = cwl[o][c * 5 + jj];
#pragma unroll
      for (int it = 0; it < 16; ++it) acc[it] = fmaf(col[it + jj], wv, acc[it]);
    }
  }
#pragma unroll
  for (int it = 0; it < 16; ++it) {
    const int t = t0 + grp * 16 + it;
    out[((size_t)b * T_ + t) * 96 + o] = fmaxf(acc[it], 0.0f);
  }
}

// ---------------- Kernel B: KAN(d) fused with sequential GRU -> out[:,:,32:96]
// Wave 0 = GRU wave: holds w_hh rows {j, 64+j, 128+j} in VGPRs, runs 64 steps per chunk
// entirely in-wave (readlane broadcast of h, NO barriers in the step loop).
// Waves 1-3 = KAN/xq waves: per chunk compute packs -> fd -> xq[t][g] = b_ih + W_ih*fd
// (h-independent, hoisted out of the serial chain).
__global__ __launch_bounds__(256, 1) void gru_kernel(
    const float* __restrict__ d, const float* __restrict__ gw, const float* __restrict__ gb,
    const float* __restrict__ bw, const float* __restrict__ sw,
    const float* __restrict__ wih_g, const float* __restrict__ whh_g,
    const float* __restrict__ bih_g, const float* __restrict__ bhh_g,
    float* __restrict__ out)
{
  __shared__ float packs[64][20];   // [t][ silu(0), pad, pad, pad, gate(4..11), bs(12..19) ]
  __shared__ float fdbuf[64][33];   // fd chunk [t][c]
  __shared__ float xq[64][192];     // xq[t][g] = b_ih[g] + dot(w_ih[g], fd[t])
  const int tid = threadIdx.x;
  const int b = blockIdx.x;
  const int w = tid >> 6;
  const int ln = tid & 63;

  // ---- wave 0: GRU weights, 3 w_hh rows per lane
  float whh3[3][64];
  float bhh3[3];
  if (w == 0) {
#pragma unroll
    for (int g3 = 0; g3 < 3; ++g3) {
      const int g = g3 * 64 + ln;
#pragma unroll
      for (int i = 0; i < 64; i += 4)
        *(float4*)&whh3[g3][i] = *(const float4*)&whh_g[(size_t)g * 64 + i];
      bhh3[g3] = bhh_g[g];
    }
  }

  // ---- waves 1-3: per-gate-class w_ih row + KAN weights
  float wihm[32];
  float bihm = 0.f;
  float swr[E_][KC_], bwr[E_], gwr[E_], gbr[E_];
  if (w >= 1) {
    const int g = (w - 1) * 64 + ln;
#pragma unroll
    for (int i = 0; i < 32; i += 4)
      *(float4*)&wihm[i] = *(const float4*)&wih_g[(size_t)g * 32 + i];
    bihm = bih_g[g];
    const int c = ln & 31;
#pragma unroll
    for (int e = 0; e < E_; ++e) {
      const float4 s0 = *(const float4*)&sw[(e * OUT_ + c) * KC_ + 0];
      const float4 s1 = *(const float4*)&sw[(e * OUT_ + c) * KC_ + 4];
      swr[e][0] = s0.x; swr[e][1] = s0.y; swr[e][2] = s0.z; swr[e][3] = s0.w;
      swr[e][4] = s1.x; swr[e][5] = s1.y; swr[e][6] = s1.z; swr[e][7] = s1.w;
      bwr[e] = bw[e * OUT_ + c];
      gwr[e] = gw[e]; gbr[e] = gb[e];
    }
  }

  float h = 0.0f;                       // wave 0, lane j holds h[j]
  float* outrow = out + (size_t)b * T_ * 96 + 32;

  for (int tc = 0; tc < T_; tc += 64) {
    // ---- phase 1 (wave 1): scalar KAN pieces for the chunk's 64 t's
    if (w == 1) {
      const float x = d[(size_t)b * T_ + tc + ln];
      float silu, gate[E_], bs[KC_];
      kan_scalars(x, gwr, gbr, silu, gate, bs);
      packs[ln][0] = silu;
      *(float4*)&packs[ln][4]  = *(float4*)&gate[0];
      *(float4*)&packs[ln][8]  = *(float4*)&gate[4];
      *(float4*)&packs[ln][12] = *(float4*)&bs[0];
      *(float4*)&packs[ln][16] = *(float4*)&bs[4];
    }
    __syncthreads();   // B1

    // ---- phase 2 (waves 1-3): fd[t][c]
    if (w >= 1) {
      const int q = tid - 64;          // 0..191
      const int c = q & 31;
      const int grp = q >> 5;          // 0..5
#pragma unroll
      for (int k = 0; k < 11; ++k) {
        const int tl = grp * 11 + k;
        if (tl < 64) {
          const float silu = packs[tl][0];
          float gatev[E_], bsv[KC_];
          *(float4*)&gatev[0] = *(float4*)&packs[tl][4];
          *(float4*)&gatev[4] = *(float4*)&packs[tl][8];
          *(float4*)&bsv[0]   = *(float4*)&packs[tl][12];
          *(float4*)&bsv[4]   = *(float4*)&packs[tl][16];
          float accb = 0.f, accs = 0.f;
#pragma unroll
          for (int e = 0; e < E_; ++e) {
            accb = fmaf(gatev[e], bwr[e], accb);
            float dot = bsv[0]*swr[e][0] + bsv[1]*swr[e][1] + bsv[2]*swr[e][2] + bsv[3]*swr[e][3]
                      + bsv[4]*swr[e][4] + bsv[5]*swr[e][5] + bsv[6]*swr[e][6] + bsv[7]*swr[e][7];
            accs = fmaf(gatev[e], dot, accs);
          }
          fdbuf[tl][c] = fmaf(silu, accb, accs);
        }
      }
    }
    __syncthreads();   // B2

    // ---- phase 3 (waves 1-3): xq[t][g], one gate class per wave
    if (w >= 1) {
      const int gbase = (w - 1) * 64;
      float fdv_next = fdbuf[0][ln & 31];
      for (int t = 0; t < 64; ++t) {
        const float fdv = fdv_next;
        if (t < 63) fdv_next = fdbuf[t + 1][ln & 31];
        float x0 = bihm, x1 = 0.f;
#pragma unroll
        for (int i0 = 0; i0 < 32; i0 += 16) {
          float fb[16];
#pragma unroll
          for (int k = 0; k < 16; ++k) fb[k] = rlane(fdv, i0 + k);
#pragma unroll
          for (int k = 0; k < 16; k += 2) {
            x0 = fmaf(fb[k],     wihm[i0 + k],     x0);
            x1 = fmaf(fb[k + 1], wihm[i0 + k + 1], x1);
          }
        }
        xq[t][gbase + ln] = x0 + x1;
      }
    }
    __syncthreads();   // B3

    // ---- phase 4 (wave 0): 64 GRU steps, barrier-free
    if (w == 0) {
#pragma unroll 1
      for (int s = 0; s < 64; ++s) {
        const float xr = xq[s][ln];
        const float xz = xq[s][64 + ln];
        const float xn = xq[s][128 + ln];
        float ar0 = 0.f, ar1 = 0.f, az0 = 0.f, az1 = 0.f, an0 = 0.f, an1 = 0.f;
#pragma unroll
        for (int i0 = 0; i0 < 64; i0 += 16) {
          float hb[16];
#pragma unroll
          for (int k = 0; k < 16; ++k) hb[k] = rlane(h, i0 + k);
#pragma unroll
          for (int k = 0; k < 16; k += 2) {
            ar0 = fmaf(hb[k],     whh3[0][i0 + k],     ar0);
            ar1 = fmaf(hb[k + 1], whh3[0][i0 + k + 1], ar1);
            az0 = fmaf(hb[k],     whh3[1][i0 + k],     az0);
            az1 = fmaf(hb[k + 1], whh3[1][i0 + k + 1], az1);
            an0 = fmaf(hb[k],     whh3[2][i0 + k],     an0);
            an1 = fmaf(hb[k + 1], whh3[2][i0 + k + 1], an1);
          }
        }
        const float hr = bhh3[0] + ar0 + ar1;
        const float hz = bhh3[1] + az0 + az1;
        const float hn = bhh3[2] + an0 + an1;
        const float r = fsig(xr + hr);
        const float z = fsig(xz + hz);
        const float n = ftanh_(fmaf(r, hn, xn));
        h = n + z * (h - n);
        outrow[(size_t)(tc + s) * 96 + ln] = h;
      }
    }
    __syncthreads();   // B4 (protect packs/fdbuf/xq for next chunk)
  }
}

extern "C" void kernel_launch(void* const* d_in, const int* in_sizes, int n_in,
                              void* d_out, int out_size, void* d_ws, size_t ws_size,
                              hipStream_t stream) {
  (void)in_sizes; (void)n_in; (void)out_size; (void)d_ws; (void)ws_size;
  const float* a        = (const float*)d_in[0];
  const float* d        = (const float*)d_in[1];
  const float* gate_w_a = (const float*)d_in[2];
  const float* gate_b_a = (const float*)d_in[3];
  const float* base_w_a = (const float*)d_in[4];
  const float* spln_w_a = (const float*)d_in[5];
  const float* gate_w_d = (const float*)d_in[6];
  const float* gate_b_d = (const float*)d_in[7];
  const float* base_w_d = (const float*)d_in[8];
  const float* spln_w_d = (const float*)d_in[9];
  const float* conv_w   = (const float*)d_in[10];
  const float* conv_b   = (const float*)d_in[11];
  const float* w_ih     = (const float*)d_in[12];
  const float* w_hh     = (const float*)d_in[13];
  const float* b_ih     = (const float*)d_in[14];
  const float* b_hh     = (const float*)d_in[15];
  float* out = (float*)d_out;

  dim3 gridA(T_ / TILE_A, B_);
  kan_conv_kernel<<<gridA, 256, 0, stream>>>(a, gate_w_a, gate_b_a, base_w_a, spln_w_a,
                                             conv_w, conv_b, out);
  gru_kernel<<<B_, 256, 0, stream>>>(d, gate_w_d, gate_b_d, base_w_d, spln_w_d,
                                     w_ih, w_hh, b_ih, b_hh, out);
}

// Round 3
// 805.430 us; speedup vs baseline: 2.7405x; 2.0399x over previous
//
#include <hip/hip_runtime.h>
#include <cstdint>

typedef _Float16 half2_t __attribute__((ext_vector_type(2)));

#define B_   128
#define T_   2048
#define E_   8
#define OUT_ 32
#define HID_ 64
#define KC_  8
#define NCH  (T_ / 64)   // 32 chunks of 64 timesteps

__device__ __forceinline__ float frcp(float x) { return __builtin_amdgcn_rcpf(x); }
__device__ __forceinline__ float fsig(float x) { return frcp(1.0f + __expf(-x)); }
__device__ __forceinline__ float ftanh_(float x) {
  float ax = fabsf(x);
  float e = __expf(2.0f * ax);
  float t = 1.0f - 2.0f * frcp(e + 1.0f);
  return copysignf(t, x);
}

__device__ __forceinline__ float fdot2_(half2_t a, half2_t b, float c) {
#if __has_builtin(__builtin_amdgcn_fdot2)
  return __builtin_amdgcn_fdot2(a, b, c, false);
#else
  return fmaf((float)a.x, (float)b.x, fmaf((float)a.y, (float)b.y, c));
#endif
}

__device__ __forceinline__ half2_t u2h2(unsigned u) {
  return __builtin_bit_cast(half2_t, u);
}

// Per-(b,t) scalar KAN pieces. All b-spline denominators fold to compile-time constants.
__device__ __forceinline__ void kan_scalars(float x, const float* gwr, const float* gbr,
                                            float& silu, float* gate, float* bs) {
  silu = x * fsig(x);
  float le[E_];
  float m = -1e30f;
#pragma unroll
  for (int e = 0; e < E_; ++e) { le[e] = fmaf(x, gwr[e], gbr[e]); m = fmaxf(m, le[e]); }
  float s = 0.f;
#pragma unroll
  for (int e = 0; e < E_; ++e) { gate[e] = __expf(le[e] - m); s += gate[e]; }
  float inv = frcp(s);
#pragma unroll
  for (int e = 0; e < E_; ++e) gate[e] *= inv;
  float g[12];
#pragma unroll
  for (int i = 0; i < 12; ++i) g[i] = (float)(i - 3) * 0.4f - 1.0f;
  float bb[11];
#pragma unroll
  for (int i = 0; i < 11; ++i) bb[i] = (x >= g[i] && x < g[i + 1]) ? 1.0f : 0.0f;
#pragma unroll
  for (int k = 1; k <= 3; ++k) {
#pragma unroll
    for (int i = 0; i < 11 - k; ++i) {
      const float dl = 1.0f / (g[i + k] - g[i]);
      const float dr = 1.0f / (g[i + k + 1] - g[i + 1]);
      float left  = (x - g[i]) * dl;
      float right = (g[i + k + 1] - x) * dr;
      bb[i] = left * bb[i] + right * bb[i + 1];
    }
  }
#pragma unroll
  for (int i = 0; i < KC_; ++i) bs[i] = bb[i];
}

// ---------------- Kernel A: KAN(a) fused with Conv1d(k=5,'SAME') + ReLU -> out[:,:,0:32]
#define TILE_A 128
__global__ __launch_bounds__(256) void kan_conv_kernel(
    const float* __restrict__ a, const float* __restrict__ gw, const float* __restrict__ gb,
    const float* __restrict__ bw, const float* __restrict__ sw,
    const float* __restrict__ cw, const float* __restrict__ cb, float* __restrict__ out)
{
  __shared__ float fa[OUT_][TILE_A + 8];
  __shared__ float cwl[OUT_][161];
  __shared__ float swl[E_][OUT_][KC_];
  __shared__ float bwl[E_][OUT_];
  __shared__ float gwl[E_], gbl[E_];
  const int tid = threadIdx.x;
  const int b = blockIdx.y;
  const int t0 = blockIdx.x * TILE_A;

  for (int i = tid; i < OUT_ * OUT_ * 5; i += 256) cwl[i / 160][i % 160] = cw[i];
  for (int i = tid; i < E_ * OUT_ * KC_; i += 256) ((float*)swl)[i] = sw[i];
  for (int i = tid; i < E_ * OUT_; i += 256) ((float*)bwl)[i] = bw[i];
  if (tid < E_) { gwl[tid] = gw[tid]; gbl[tid] = gb[tid]; }
  __syncthreads();

  if (tid < TILE_A + 4) {
    const int i = tid;
    const int t = t0 + i - 2;
    const bool inr = (t >= 0) && (t < T_);
    const float x = inr ? a[(size_t)b * T_ + t] : 0.0f;
    float gwr[E_], gbr[E_];
#pragma unroll
    for (int e = 0; e < E_; ++e) { gwr[e] = gwl[e]; gbr[e] = gbl[e]; }
    float silu, gate[E_], bs[KC_];
    kan_scalars(x, gwr, gbr, silu, gate, bs);
#pragma unroll 4
    for (int cc = 0; cc < OUT_; ++cc) {
      float accb = 0.f, accs = 0.f;
#pragma unroll
      for (int e = 0; e < E_; ++e) {
        accb = fmaf(gate[e], bwl[e][cc], accb);
        const float4 s0 = *(const float4*)&swl[e][cc][0];
        const float4 s1 = *(const float4*)&swl[e][cc][4];
        float dot = bs[0]*s0.x + bs[1]*s0.y + bs[2]*s0.z + bs[3]*s0.w
                  + bs[4]*s1.x + bs[5]*s1.y + bs[6]*s1.z + bs[7]*s1.w;
        accs = fmaf(gate[e], dot, accs);
      }
      fa[cc][i] = inr ? fmaf(silu, accb, accs) : 0.0f;
    }
  }
  __syncthreads();

  const int o = tid & 31;
  const int grp = tid >> 5;
  const float bias = cb[o];
  float acc[16];
#pragma unroll
  for (int it = 0; it < 16; ++it) acc[it] = bias;
  for (int c = 0; c < OUT_; ++c) {
    float col[20];
#pragma unroll
    for (int q = 0; q < 5; ++q)
      *(float4*)&col[q * 4] = *(const float4*)&fa[c][grp * 16 + q * 4];
#pragma unroll
    for (int jj = 0; jj < 5; ++jj) {
      const float wv = cwl[o][c * 5 + jj];
#pragma unroll
      for (int it = 0; it < 16; ++it) acc[it] = fmaf(col[it + jj], wv, acc[it]);
    }
  }
#pragma unroll
  for (int it = 0; it < 16; ++it) {
    const int t = t0 + grp * 16 + it;
    out[((size_t)b * T_ + t) * 96 + o] = fmaxf(acc[it], 0.0f);
  }
}

// ---------------- Kernel B: KAN(d) fused with sequential GRU -> out[:,:,32:96]
// Producer/consumer pipeline:
//   waves 1-3 (producers): per chunk, each wave self-sufficiently computes
//     xq[t][g] = b_ih[g] + W_ih[g]·fd[t]  for its 64-gate class, using KAN weights
//     FOLDED into W_ih:  A[g][e] = Σ_c wih[g][c]·bw[e][c],
//                        B[g][e][k] = Σ_c wih[g][c]·sw[e][c][k]  (precomputed once),
//     so xq[t][g] = bih + Σ_e gate[t][e]·( silu[t]·A[e] + Σ_k bs[t][k]·B[e][k] ).
//     Intra-wave only (packsw write -> lgkmcnt -> read): no cross-wave sync needed.
//   wave 0 (consumer): runs 64 GRU steps on the PREVIOUS chunk's xq (double-buffered),
//     w_hh held as packed f16 pairs (96 VGPRs, no spill), h broadcast via a 128-byte
//     LDS f16 buffer read back as 16 broadcast b64 loads, dots via v_dot2_f32_f16
//     with f32 accumulation. One uniform __syncthreads per chunk iteration.
__global__ __launch_bounds__(256, 1) void gru_kernel(
    const float* __restrict__ d, const float* __restrict__ gw, const float* __restrict__ gb,
    const float* __restrict__ bw, const float* __restrict__ sw,
    const float* __restrict__ wih_g, const float* __restrict__ whh_g,
    const float* __restrict__ bih_g, const float* __restrict__ bhh_g,
    float* __restrict__ out)
{
  __shared__ _Float16 xq[2][64][192];         // 49152 B, double-buffered pre-activations
  __shared__ float packsw[3][64][16];         // 12288 B: per wave, per t: gate[0..7], silu@8, bs f16x2 @10..13
  __shared__ unsigned short hbc[64];          // 128 B: h broadcast as f16

  const int tid = threadIdx.x;
  const int b = blockIdx.x;
  const int w = tid >> 6;
  const int ln = tid & 63;

  // ---- wave 0: w_hh as f16 pairs (lane ln owns gate rows ln, 64+ln, 128+ln)
  half2_t whhp[3][32];
  float bhh3[3];
  if (w == 0) {
#pragma unroll
    for (int g3 = 0; g3 < 3; ++g3) {
      const int g = g3 * 64 + ln;
#pragma unroll
      for (int i = 0; i < 64; i += 4) {
        const float4 v = *(const float4*)&whh_g[(size_t)g * 64 + i];
        half2_t p0, p1;
        p0.x = (_Float16)v.x; p0.y = (_Float16)v.y;
        p1.x = (_Float16)v.z; p1.y = (_Float16)v.w;
        whhp[g3][i / 2]     = p0;
        whhp[g3][i / 2 + 1] = p1;
      }
      bhh3[g3] = bhh_g[g];
    }
  }

  // ---- waves 1-3: folded weights for gate g = (w-1)*64 + ln
  float A_[E_];
  half2_t Beh[E_][4];
  float bihr = 0.f;
  float gwr[E_], gbr[E_];
  const int p3 = (w >= 1) ? (w - 1) : 0;
  if (w >= 1) {
    const int g = p3 * 64 + ln;
    float wihr[32];
#pragma unroll
    for (int i = 0; i < 32; i += 4)
      *(float4*)&wihr[i] = *(const float4*)&wih_g[(size_t)g * 32 + i];
    bihr = bih_g[g];
#pragma unroll
    for (int e = 0; e < E_; ++e) { gwr[e] = gw[e]; gbr[e] = gb[e]; }
    // A[e] = sum_c wihr[c] * bw[e][c]
#pragma unroll
    for (int e = 0; e < E_; ++e) {
      float acc = 0.f;
#pragma unroll 4
      for (int c = 0; c < 32; c += 4) {
        const float4 bv = *(const float4*)&bw[e * OUT_ + c];
        acc = fmaf(wihr[c], bv.x, acc);
        acc = fmaf(wihr[c + 1], bv.y, acc);
        acc = fmaf(wihr[c + 2], bv.z, acc);
        acc = fmaf(wihr[c + 3], bv.w, acc);
      }
      A_[e] = acc;
    }
    // B[e][k] = sum_c wihr[c] * sw[e][c][k], packed to f16 pairs over k
#pragma unroll
    for (int e = 0; e < E_; ++e) {
      float bk[KC_];
#pragma unroll
      for (int k = 0; k < KC_; ++k) bk[k] = 0.f;
#pragma unroll 4
      for (int c = 0; c < 32; ++c) {
        const float4 s0 = *(const float4*)&sw[(e * OUT_ + c) * KC_ + 0];
        const float4 s1 = *(const float4*)&sw[(e * OUT_ + c) * KC_ + 4];
        const float wc = wihr[c];
        bk[0] = fmaf(wc, s0.x, bk[0]); bk[1] = fmaf(wc, s0.y, bk[1]);
        bk[2] = fmaf(wc, s0.z, bk[2]); bk[3] = fmaf(wc, s0.w, bk[3]);
        bk[4] = fmaf(wc, s1.x, bk[4]); bk[5] = fmaf(wc, s1.y, bk[5]);
        bk[6] = fmaf(wc, s1.z, bk[6]); bk[7] = fmaf(wc, s1.w, bk[7]);
      }
#pragma unroll
      for (int q = 0; q < 4; ++q) {
        half2_t hp;
        hp.x = (_Float16)bk[2 * q];
        hp.y = (_Float16)bk[2 * q + 1];
        Beh[e][q] = hp;
      }
    }
  }

  float h = 0.0f;                       // wave 0, lane ln holds h[ln] in f32
  float* outrow = out + (size_t)b * T_ * 96 + 32;
  const size_t db = (size_t)b * T_;

  for (int ic = 0; ic <= NCH; ++ic) {
    // ================= producers: chunk ic -> xq[ic&1] =================
    if (w >= 1 && ic < NCH) {
      const int p = ic & 1;
      // (1) scalar KAN pieces for t = ln (one t per lane, no redundancy)
      {
        const float x = d[db + ic * 64 + ln];
        float silu, gate[E_], bs[KC_];
        kan_scalars(x, gwr, gbr, silu, gate, bs);
        float* prow = &packsw[p3][ln][0];
        *(float4*)&prow[0] = *(float4*)&gate[0];
        *(float4*)&prow[4] = *(float4*)&gate[4];
        prow[8] = silu;
        half2_t* bsp = (half2_t*)&prow[10];
#pragma unroll
        for (int q = 0; q < 4; ++q) {
          half2_t hv;
          hv.x = (_Float16)bs[2 * q];
          hv.y = (_Float16)bs[2 * q + 1];
          bsp[q] = hv;
        }
      }
      asm volatile("" ::: "memory");   // order pack-write before t-loop reads (intra-wave)
      // (2) xq[t][g] for all 64 t via folded weights (broadcast LDS reads)
#pragma unroll 2
      for (int t = 0; t < 64; ++t) {
        const float* pr = &packsw[p3][t][0];
        const float4 g0 = *(const float4*)&pr[0];
        const float4 g1 = *(const float4*)&pr[4];
        const float silu_t = pr[8];
        const half2_t* bsp = (const half2_t*)&pr[10];
        const half2_t b0 = bsp[0], b1 = bsp[1], b2 = bsp[2], b3 = bsp[3];
        float acc = bihr;
        {
          float in0 = silu_t * A_[0];
          in0 = fdot2_(b0, Beh[0][0], in0); in0 = fdot2_(b1, Beh[0][1], in0);
          in0 = fdot2_(b2, Beh[0][2], in0); in0 = fdot2_(b3, Beh[0][3], in0);
          acc = fmaf(g0.x, in0, acc);
          float in1 = silu_t * A_[1];
          in1 = fdot2_(b0, Beh[1][0], in1); in1 = fdot2_(b1, Beh[1][1], in1);
          in1 = fdot2_(b2, Beh[1][2], in1); in1 = fdot2_(b3, Beh[1][3], in1);
          acc = fmaf(g0.y, in1, acc);
          float in2 = silu_t * A_[2];
          in2 = fdot2_(b0, Beh[2][0], in2); in2 = fdot2_(b1, Beh[2][1], in2);
          in2 = fdot2_(b2, Beh[2][2], in2); in2 = fdot2_(b3, Beh[2][3], in2);
          acc = fmaf(g0.z, in2, acc);
          float in3 = silu_t * A_[3];
          in3 = fdot2_(b0, Beh[3][0], in3); in3 = fdot2_(b1, Beh[3][1], in3);
          in3 = fdot2_(b2, Beh[3][2], in3); in3 = fdot2_(b3, Beh[3][3], in3);
          acc = fmaf(g0.w, in3, acc);
          float in4 = silu_t * A_[4];
          in4 = fdot2_(b0, Beh[4][0], in4); in4 = fdot2_(b1, Beh[4][1], in4);
          in4 = fdot2_(b2, Beh[4][2], in4); in4 = fdot2_(b3, Beh[4][3], in4);
          acc = fmaf(g1.x, in4, acc);
          float in5 = silu_t * A_[5];
          in5 = fdot2_(b0, Beh[5][0], in5); in5 = fdot2_(b1, Beh[5][1], in5);
          in5 = fdot2_(b2, Beh[5][2], in5); in5 = fdot2_(b3, Beh[5][3], in5);
          acc = fmaf(g1.y, in5, acc);
          float in6 = silu_t * A_[6];
          in6 = fdot2_(b0, Beh[6][0], in6); in6 = fdot2_(b1, Beh[6][1], in6);
          in6 = fdot2_(b2, Beh[6][2], in6); in6 = fdot2_(b3, Beh[6][3], in6);
          acc = fmaf(g1.z, in6, acc);
          float in7 = silu_t * A_[7];
          in7 = fdot2_(b0, Beh[7][0], in7); in7 = fdot2_(b1, Beh[7][1], in7);
          in7 = fdot2_(b2, Beh[7][2], in7); in7 = fdot2_(b3, Beh[7][3], in7);
          acc = fmaf(g1.w, in7, acc);
        }
        xq[p][t][p3 * 64 + ln] = (_Float16)acc;
      }
    }

    // ================= consumer: chunk ic-1 from xq[(ic-1)&1] =================
    if (w == 0 && ic >= 1) {
      const int jc = ic - 1;
      const int p = jc & 1;
      const int tb = jc * 64;
#pragma unroll 1
      for (int s = 0; s < 64; ++s) {
        const float xr = (float)xq[p][s][ln];
        const float xz = (float)xq[p][s][64 + ln];
        const float xn = (float)xq[p][s][128 + ln];
        hbc[ln] = __builtin_bit_cast(unsigned short, (_Float16)h);
        asm volatile("" ::: "memory");   // order h-broadcast write before reads
        float ar0 = 0.f, ar1 = 0.f, az0 = 0.f, az1 = 0.f, an0 = 0.f, an1 = 0.f;
        const uint2* hq = (const uint2*)hbc;
#pragma unroll
        for (int k = 0; k < 16; ++k) {
          const uint2 u = hq[k];                 // broadcast b64: h[4k..4k+3] as f16
          const half2_t p0 = u2h2(u.x);
          const half2_t p1 = u2h2(u.y);
          ar0 = fdot2_(whhp[0][2 * k], p0, ar0);
          ar1 = fdot2_(whhp[0][2 * k + 1], p1, ar1);
          az0 = fdot2_(whhp[1][2 * k], p0, az0);
          az1 = fdot2_(whhp[1][2 * k + 1], p1, az1);
          an0 = fdot2_(whhp[2][2 * k], p0, an0);
          an1 = fdot2_(whhp[2][2 * k + 1], p1, an1);
        }
        const float hr = bhh3[0] + ar0 + ar1;
        const float hz = bhh3[1] + az0 + az1;
        const float hn = bhh3[2] + an0 + an1;
        const float r = fsig(xr + hr);
        const float z = fsig(xz + hz);
        const float n = ftanh_(fmaf(r, hn, xn));
        h = n + z * (h - n);
        outrow[(size_t)(tb + s) * 96 + ln] = h;
      }
    }
    __syncthreads();   // one uniform barrier per chunk iteration
  }
}

extern "C" void kernel_launch(void* const* d_in, const int* in_sizes, int n_in,
                              void* d_out, int out_size, void* d_ws, size_t ws_size,
                              hipStream_t stream) {
  (void)in_sizes; (void)n_in; (void)out_size; (void)d_ws; (void)ws_size;
  const float* a        = (const float*)d_in[0];
  const float* d        = (const float*)d_in[1];
  const float* gate_w_a = (const float*)d_in[2];
  const float* gate_b_a = (const float*)d_in[3];
  const float* base_w_a = (const float*)d_in[4];
  const float* spln_w_a = (const float*)d_in[5];
  const float* gate_w_d = (const float*)d_in[6];
  const float* gate_b_d = (const float*)d_in[7];
  const float* base_w_d = (const float*)d_in[8];
  const float* spln_w_d = (const float*)d_in[9];
  const float* conv_w   = (const float*)d_in[10];
  const float* conv_b   = (const float*)d_in[11];
  const float* w_ih     = (const float*)d_in[12];
  const float* w_hh     = (const float*)d_in[13];
  const float* b_ih     = (const float*)d_in[14];
  const float* b_hh     = (const float*)d_in[15];
  float* out = (float*)d_out;

  dim3 gridA(T_ / TILE_A, B_);
  kan_conv_kernel<<<gridA, 256, 0, stream>>>(a, gate_w_a, gate_b_a, base_w_a, spln_w_a,
                                             conv_w, conv_b, out);
  gru_kernel<<<B_, 256, 0, stream>>>(d, gate_w_d, gate_b_d, base_w_d, spln_w_d,
                                     w_ih, w_hh, b_ih, b_hh, out);
}